// Round 5
// baseline (4087.289 us; speedup 1.0000x reference)
//
#include <hip/hip_runtime.h>
#include <cstdint>
#include <cstddef>

#define T_STEPS 512
#define BATCH   64
#define HD      1024
#define BH      (BATCH * HD)   // 65536
#define NBLK    256
#define NSG     4              // independent sub-grids (batch groups)
#define BSG     16             // batches per sub-grid
#define JBLK    16             // j columns per block (tier A2 kernel)
#define CBYTES  ((size_t)BH * 4)   // one c buffer: interleaved hi/lo, 4B/value

using half8   = __attribute__((ext_vector_type(8))) _Float16;
using half4   = __attribute__((ext_vector_type(4))) _Float16;
using floatx4 = __attribute__((ext_vector_type(4))) float;
using float4v = __attribute__((ext_vector_type(4))) float;
using int4v   = __attribute__((ext_vector_type(4))) int;
using u64     = unsigned long long;

__device__ __forceinline__ float sigmoidf_(float x) { return 1.0f / (1.0f + __expf(-x)); }

__device__ __forceinline__ half8 cvt_h8(float4v a, float4v b) {
    half8 r;
    r[0] = (_Float16)a[0]; r[1] = (_Float16)a[1];
    r[2] = (_Float16)a[2]; r[3] = (_Float16)a[3];
    r[4] = (_Float16)b[0]; r[5] = (_Float16)b[1];
    r[6] = (_Float16)b[2]; r[7] = (_Float16)b[3];
    return r;
}

__device__ __forceinline__ u64 pack_lo16(unsigned a, unsigned b, unsigned c, unsigned d) {
    return (u64)(a & 0xffffu) | ((u64)(b & 0xffffu) << 16)
         | ((u64)(c & 0xffffu) << 32) | ((u64)(d & 0xffffu) << 48);
}
__device__ __forceinline__ u64 pack_hi16(unsigned a, unsigned b, unsigned c, unsigned d) {
    return (u64)(a >> 16) | ((u64)(b >> 16) << 16)
         | ((u64)(c >> 16) << 32) | ((u64)(d >> 16) << 48);
}

// tagged hi/lo split: force bit0 of hi to parity p, lo absorbs the error
// exactly; then force bit0 of lo to p (error ~2^-21 relative — negligible).
// Returns packed (hi | lo<<16).
__device__ __forceinline__ unsigned tag_pack(float c, unsigned p) {
    unsigned hb = (unsigned)__builtin_bit_cast(unsigned short, (_Float16)c);
    hb = (hb & 0xFFFEu) | p;
    _Float16 hf = __builtin_bit_cast(_Float16, (unsigned short)hb);
    unsigned lb = (unsigned)__builtin_bit_cast(unsigned short, (_Float16)(c - (float)hf));
    lb = (lb & 0xFFFEu) | p;
    return hb | (lb << 16);
}

// ---------------- workspace layout ----------------
static const size_t BAR_GRP_OFF  = 0;        // legacy barrier (tier A/B)
static const size_t BAR_ROOT_OFF = 20480;
static const size_t CH_OFF  = 24576;                               // A2: c3 (3x256KB); legacy: ch
static const size_t CL_OFF  = CH_OFF + (size_t)2 * BH * 2;         // legacy cl
static const size_t WX_OFF  = 1u << 20;                            // 8 MB
static const size_t WHH_OFF = WX_OFF  + (size_t)8 * 1024 * 1024;   // 8 MB
static const size_t WHL_OFF = WHH_OFF + (size_t)8 * 1024 * 1024;   // 8 MB
static const size_t XH_OFF  = WHL_OFF + (size_t)8 * 1024 * 1024;   // @25MB
static const size_t X4_OFF  = XH_OFF;                              // A2: X4 f16 [32768][4096]
static const size_t TIER_A2_WS = X4_OFF + (size_t)32768 * 4096 * 2;  // ~281 MB
static const size_t TIER_A_WS  = XH_OFF + (size_t)T_STEPS * BH * 2;  // 89 MB
static const size_t TIER_B_WS  = XH_OFF;                             // 25 MB

// ---------------- prep kernels ----------------
__global__ void prep_zero(int* bar) {
    int i = blockIdx.x * 256 + threadIdx.x;
    if (i < 6144) bar[i] = 0;
}

// Poison the 3 c buffers so un-written data NEVER validates:
// buf0 first read at t=0 (parity 0) -> poison bit0=1; buf1 first read t=1
// (parity 1) -> poison bit0=0; buf2 first read t=2 (parity 0) -> bit0=1.
__global__ void prep_poison(unsigned* c3) {
    int i = blockIdx.x * 256 + threadIdx.x;   // 3 * 65536 dwords
    if (i < 196608) {
        int buf = i >> 16;
        c3[i] = (buf == 1) ? 0u : 0x00010001u;
    }
}

__global__ void prep_w(const float* __restrict__ Wx, const float* __restrict__ Wh,
                       _Float16* __restrict__ wx16,
                       _Float16* __restrict__ whh, _Float16* __restrict__ whl) {
    int i = blockIdx.x * 256 + threadIdx.x;
    if (i < 4 * HD * HD) {
        wx16[i] = (_Float16)Wx[i];
        float w = Wh[i];
        _Float16 h = (_Float16)w;
        whh[i] = h;
        whl[i] = (_Float16)(w - (float)h);
    }
}

__global__ void prep_x(const float* __restrict__ X, _Float16* __restrict__ xh) {
    size_t i = (size_t)blockIdx.x * 256 + threadIdx.x;
    if (i < (size_t)T_STEPS * BH) xh[i] = (_Float16)X[i];
}

// ---------------- X4 GEMM: x4[32768][4096] = X[32768][1024] @ wx16^T ----------------
__global__ __launch_bounds__(256) void x4_gemm(
    const float* __restrict__ X,
    const _Float16* __restrict__ wx16,
    _Float16* __restrict__ x4)
{
    __shared__ _Float16 sA[128][40];
    __shared__ _Float16 sB[128][40];

    const int tid  = threadIdx.x;
    const int wave = tid >> 6;
    const int lane = tid & 63;
    const int m0 = blockIdx.x * 128, n0 = blockIdx.y * 128;
    const int wm = (wave & 1) * 64,  wn = (wave >> 1) * 64;
    const int fm = lane & 15, q = lane >> 4;

    floatx4 acc[4][4];
    #pragma unroll
    for (int i = 0; i < 4; i++)
        #pragma unroll
        for (int j = 0; j < 4; j++)
            acc[i][j] = (floatx4){0.f, 0.f, 0.f, 0.f};

    for (int k0 = 0; k0 < 1024; k0 += 32) {
        {
            const int kq = (tid & 7) * 4;
            const int rb = tid >> 3;
            #pragma unroll
            for (int it = 0; it < 4; it++) {
                int row = rb + it * 32;
                float4v v = *(const float4v*)(X + (size_t)(m0 + row) * 1024 + k0 + kq);
                half4 h; h[0] = (_Float16)v[0]; h[1] = (_Float16)v[1];
                h[2] = (_Float16)v[2]; h[3] = (_Float16)v[3];
                *(half4*)&sA[row][kq] = h;
            }
        }
        {
            const int half = tid & 1;
            const int row  = tid >> 1;
            const _Float16* src = wx16 + (size_t)(n0 + row) * 1024 + k0 + half * 16;
            *(half8*)&sB[row][half * 16]     = *(const half8*)(src);
            *(half8*)&sB[row][half * 16 + 8] = *(const half8*)(src + 8);
        }
        __syncthreads();

        half8 af[4], bf[4];
        #pragma unroll
        for (int i = 0; i < 4; i++) af[i] = *(const half8*)&sA[wm + 16 * i + fm][q * 8];
        #pragma unroll
        for (int j = 0; j < 4; j++) bf[j] = *(const half8*)&sB[wn + 16 * j + fm][q * 8];
        #pragma unroll
        for (int i = 0; i < 4; i++)
            #pragma unroll
            for (int j = 0; j < 4; j++)
                acc[i][j] = __builtin_amdgcn_mfma_f32_16x16x32_f16(af[i], bf[j], acc[i][j], 0, 0, 0);
        __syncthreads();
    }

    #pragma unroll
    for (int i = 0; i < 4; i++)
        #pragma unroll
        for (int j = 0; j < 4; j++)
            #pragma unroll
            for (int r = 0; r < 4; r++) {
                int row = m0 + wm + 16 * i + q * 4 + r;
                int col = n0 + wn + 16 * j + fm;
                x4[(size_t)row * 4096 + col] = (_Float16)acc[i][j][r];
            }
}

// ---------------- legacy grid barrier (tier A/B kernel) ----------------
__device__ __forceinline__ void grid_bar(int* grp, int* root, int slot) {
    __syncthreads();
    if (threadIdx.x == 0) {
        int g = blockIdx.x >> 5;
        int v = __hip_atomic_fetch_add(&grp[slot * 8 + g], 1,
                                       __ATOMIC_ACQ_REL, __HIP_MEMORY_SCOPE_AGENT);
        if (v == 31)
            __hip_atomic_fetch_add(&root[slot], 1,
                                   __ATOMIC_ACQ_REL, __HIP_MEMORY_SCOPE_AGENT);
        while (__hip_atomic_load(&root[slot], __ATOMIC_RELAXED,
                                 __HIP_MEMORY_SCOPE_AGENT) < 8)
            __builtin_amdgcn_s_sleep(2);
        (void)__hip_atomic_load(&root[slot], __ATOMIC_ACQUIRE,
                                __HIP_MEMORY_SCOPE_AGENT);
    }
    __syncthreads();
}

// ---------------- persistent recurrence (tier A2, self-validating exchange) ----------------
// 4 sub-grids x 64 blocks x 512 threads; block = 16 j x 4 gates; wave =
// K-chunk 128. c exchange: 3 rotating buffers of 16B units [4x hi f16, 4x lo
// f16], EVERY f16 carries step parity in bit0 (hi tag error absorbed exactly
// by lo). Consumers poll-validate the data directly -> NO flags, NO store
// drain, NO end-of-step sync. Safety: buffer(period 3) x parity(period 2)
// gives unique signature mod 6; all-to-all read deps bound slip <= ~1 so
// buffer t%3 can only hold S_t (valid) or S_{t-3} (parity mismatch).
__global__ __launch_bounds__(512, 1) void lstm_persist5(
    const _Float16* __restrict__ x4,   // [T*B][4096]
    const float* __restrict__ h0, const float* __restrict__ c0,
    const float* __restrict__ bias, const int* __restrict__ mask,
    const _Float16* __restrict__ whh, const _Float16* __restrict__ whl,
    char* __restrict__ c3,
    float* __restrict__ out)
{
    __shared__ float s_pre[2][8][4][16][18];   // 73.7 KB (double-buffered)
    __shared__ float s_h[256], s_c[256];

    const int tid  = threadIdx.x;
    const int wave = tid >> 6;     // 0..7 = K-chunk
    const int lane = tid & 63;
    const int sg   = blockIdx.x >> 6;   // 0..3
    const int lb   = blockIdx.x & 63;   // 0..63
    const int b0   = sg * BSG;
    const int j0   = lb * JBLK;

    const int nn    = lane & 15;          // j-local (B-frag row)
    const int q     = lane >> 4;
    const int kbase = wave * 128 + q * 8;
    const int arow  = lane & 15;          // batch-local (A-frag row)

    // ---- all weights (hi + lo) into registers: 4 gates x 4 k-iters ----
    half8 wh_[4][4], wl_[4][4];
    #pragma unroll
    for (int g = 0; g < 4; g++) {
        const size_t wr = (size_t)(g * HD + j0 + nn) * HD + kbase;
        #pragma unroll
        for (int k = 0; k < 4; k++) {
            wh_[g][k] = *(const half8*)(whh + wr + k * 32);
            wl_[g][k] = *(const half8*)(whl + wr + k * 32);
        }
    }

    // ---- init gate state, publish tagged S_0 (buffer 0, parity 0) ----
    float biasr[4] = {0.f, 0.f, 0.f, 0.f};
    float xg[4]    = {0.f, 0.f, 0.f, 0.f};
    int   mv       = 0;
    if (tid < 256) {
        int bl = tid >> 4, n = tid & 15;
        int b = b0 + bl, j = j0 + n;
        float cv = c0[b * HD + j];
        s_c[tid] = cv;
        s_h[tid] = h0[b * HD + j];
        #pragma unroll
        for (int g = 0; g < 4; g++) biasr[g] = bias[g * HD + j];

        unsigned pk = tag_pack(cv, 0u);
        unsigned p1 = __shfl_down(pk, 1);
        unsigned p2 = __shfl_down(pk, 2);
        unsigned p3 = __shfl_down(pk, 3);
        if ((n & 3) == 0) {
            union { u64 qv[2]; int4v v; } sv;
            sv.qv[0] = pack_lo16(pk, p1, p2, p3);
            sv.qv[1] = pack_hi16(pk, p1, p2, p3);
            char* wp = c3 + ((size_t)b * HD + j0 + n) * 4;
            asm volatile("global_store_dwordx4 %0, %1, off sc0 sc1"
                         :: "v"(wp), "v"(sv.v) : "memory");
        }
        #pragma unroll
        for (int g = 0; g < 4; g++)
            xg[g] = (float)x4[(size_t)b * 4096 + g * HD + j];
        mv = mask[b];
    }
    // no sync / no drain needed: consumers validate the data itself

    int bi = 0;   // read-buffer index (t % 3)
    for (int t = 0; t < T_STEPS; t++) {
        const int pp = t & 1;
        const unsigned pat = pp ? 0x00010001u : 0u;

        // ---- poll-validate + load this wave's c chunk (16 b x 128 k) ----
        int4v u0, u1, u2, u3, u4, u5, u6, u7;
        const char* cp = c3 + (size_t)bi * CBYTES
                       + ((size_t)(b0 + arow) * HD + kbase) * 4;
        for (;;) {
            asm volatile(
                "global_load_dwordx4 %0, %8, off sc0 sc1\n\t"
                "global_load_dwordx4 %1, %8, off offset:16 sc0 sc1\n\t"
                "global_load_dwordx4 %2, %8, off offset:128 sc0 sc1\n\t"
                "global_load_dwordx4 %3, %8, off offset:144 sc0 sc1\n\t"
                "global_load_dwordx4 %4, %8, off offset:256 sc0 sc1\n\t"
                "global_load_dwordx4 %5, %8, off offset:272 sc0 sc1\n\t"
                "global_load_dwordx4 %6, %8, off offset:384 sc0 sc1\n\t"
                "global_load_dwordx4 %7, %8, off offset:400 sc0 sc1\n\t"
                "s_waitcnt vmcnt(0)"
                : "=&v"(u0), "=&v"(u1), "=&v"(u2), "=&v"(u3),
                  "=&v"(u4), "=&v"(u5), "=&v"(u6), "=&v"(u7)
                : "v"(cp) : "memory");
            unsigned accv =
                ((unsigned)u0[0] ^ pat) | ((unsigned)u0[1] ^ pat) | ((unsigned)u0[2] ^ pat) | ((unsigned)u0[3] ^ pat) |
                ((unsigned)u1[0] ^ pat) | ((unsigned)u1[1] ^ pat) | ((unsigned)u1[2] ^ pat) | ((unsigned)u1[3] ^ pat) |
                ((unsigned)u2[0] ^ pat) | ((unsigned)u2[1] ^ pat) | ((unsigned)u2[2] ^ pat) | ((unsigned)u2[3] ^ pat) |
                ((unsigned)u3[0] ^ pat) | ((unsigned)u3[1] ^ pat) | ((unsigned)u3[2] ^ pat) | ((unsigned)u3[3] ^ pat) |
                ((unsigned)u4[0] ^ pat) | ((unsigned)u4[1] ^ pat) | ((unsigned)u4[2] ^ pat) | ((unsigned)u4[3] ^ pat) |
                ((unsigned)u5[0] ^ pat) | ((unsigned)u5[1] ^ pat) | ((unsigned)u5[2] ^ pat) | ((unsigned)u5[3] ^ pat) |
                ((unsigned)u6[0] ^ pat) | ((unsigned)u6[1] ^ pat) | ((unsigned)u6[2] ^ pat) | ((unsigned)u6[3] ^ pat) |
                ((unsigned)u7[0] ^ pat) | ((unsigned)u7[1] ^ pat) | ((unsigned)u7[2] ^ pat) | ((unsigned)u7[3] ^ pat);
            if (__all((accv & 0x00010001u) == 0u)) break;
            __builtin_amdgcn_s_sleep(8);
        }

        // ---- unpack units into MFMA fragments ----
        union C4 { int4v i; half8 h; };
        C4 ca0, ca1, ca2, ca3, cl0, cl1, cl2, cl3;
        ca0.i = (int4v){u0[0], u0[1], u1[0], u1[1]};
        cl0.i = (int4v){u0[2], u0[3], u1[2], u1[3]};
        ca1.i = (int4v){u2[0], u2[1], u3[0], u3[1]};
        cl1.i = (int4v){u2[2], u2[3], u3[2], u3[3]};
        ca2.i = (int4v){u4[0], u4[1], u5[0], u5[1]};
        cl2.i = (int4v){u4[2], u4[3], u5[2], u5[3]};
        ca3.i = (int4v){u6[0], u6[1], u7[0], u7[1]};
        cl3.i = (int4v){u6[2], u6[3], u7[2], u7[3]};
        half8 a0 = ca0.h, a1 = ca1.h, a2 = ca2.h, a3 = ca3.h;
        half8 l0 = cl0.h, l1 = cl1.h, l2 = cl2.h, l3 = cl3.h;

        floatx4 acc[4];
        #pragma unroll
        for (int g = 0; g < 4; g++) acc[g] = (floatx4){0.f, 0.f, 0.f, 0.f};
        #pragma unroll
        for (int g = 0; g < 4; g++) {
            floatx4 t0 = acc[g];
            t0 = __builtin_amdgcn_mfma_f32_16x16x32_f16(a0, wh_[g][0], t0, 0, 0, 0);
            t0 = __builtin_amdgcn_mfma_f32_16x16x32_f16(l0, wh_[g][0], t0, 0, 0, 0);
            t0 = __builtin_amdgcn_mfma_f32_16x16x32_f16(a0, wl_[g][0], t0, 0, 0, 0);
            t0 = __builtin_amdgcn_mfma_f32_16x16x32_f16(a1, wh_[g][1], t0, 0, 0, 0);
            t0 = __builtin_amdgcn_mfma_f32_16x16x32_f16(l1, wh_[g][1], t0, 0, 0, 0);
            t0 = __builtin_amdgcn_mfma_f32_16x16x32_f16(a1, wl_[g][1], t0, 0, 0, 0);
            t0 = __builtin_amdgcn_mfma_f32_16x16x32_f16(a2, wh_[g][2], t0, 0, 0, 0);
            t0 = __builtin_amdgcn_mfma_f32_16x16x32_f16(l2, wh_[g][2], t0, 0, 0, 0);
            t0 = __builtin_amdgcn_mfma_f32_16x16x32_f16(a2, wl_[g][2], t0, 0, 0, 0);
            t0 = __builtin_amdgcn_mfma_f32_16x16x32_f16(a3, wh_[g][3], t0, 0, 0, 0);
            t0 = __builtin_amdgcn_mfma_f32_16x16x32_f16(l3, wh_[g][3], t0, 0, 0, 0);
            t0 = __builtin_amdgcn_mfma_f32_16x16x32_f16(a3, wl_[g][3], t0, 0, 0, 0);
            acc[g] = t0;
        }

        #pragma unroll
        for (int g = 0; g < 4; g++) {
            s_pre[pp][wave][g][q * 4 + 0][nn] = acc[g][0];
            s_pre[pp][wave][g][q * 4 + 1][nn] = acc[g][1];
            s_pre[pp][wave][g][q * 4 + 2][nn] = acc[g][2];
            s_pre[pp][wave][g][q * 4 + 3][nn] = acc[g][3];
        }
        __syncthreads();   // the ONLY sync per step; waves 4-7 proceed to
                           // next poll while waves 0-3 run the gate phase

        const int wi = (bi == 2) ? 0 : bi + 1;     // write buffer (t+1)%3
        if (tid < 256) {
            int bl = tid >> 4, n = tid & 15;
            int b = b0 + bl, j = j0 + n;

            float pg[4];
            #pragma unroll
            for (int g = 0; g < 4; g++) {
                float s = xg[g] + biasr[g];
                #pragma unroll
                for (int kh = 0; kh < 8; kh++)
                    s += s_pre[pp][kh][g][bl][n];
                pg[g] = s;
            }

            float c_old = s_c[tid];
            float i_g = sigmoidf_(pg[0]);
            float f_g = sigmoidf_(pg[1]);
            float o_g = sigmoidf_(pg[2]);
            float g_g = tanhf(pg[3]);
            float c_new = f_g * c_old + i_g * g_g;
            float h_new = o_g * tanhf(c_new);

            float h_out = mv ? h_new : s_h[tid];
            float c_out = mv ? c_new : c_old;
            s_h[tid] = h_out;
            s_c[tid] = c_out;

            // tagged 16B unit store (parity (t+1)&1) — fire and forget
            unsigned pk = tag_pack(c_out, (unsigned)((t + 1) & 1));
            unsigned p1 = __shfl_down(pk, 1);
            unsigned p2 = __shfl_down(pk, 2);
            unsigned p3 = __shfl_down(pk, 3);
            if ((n & 3) == 0) {
                union { u64 qv[2]; int4v v; } sv;
                sv.qv[0] = pack_lo16(pk, p1, p2, p3);
                sv.qv[1] = pack_hi16(pk, p1, p2, p3);
                char* wp = c3 + (size_t)wi * CBYTES + ((size_t)b * HD + j0 + n) * 4;
                asm volatile("global_store_dwordx4 %0, %1, off sc0 sc1"
                             :: "v"(wp), "v"(sv.v) : "memory");
            }

            out[(size_t)t * BH + (size_t)b * HD + j] = h_out;
            if (t == T_STEPS - 1) {
                size_t tail = (size_t)T_STEPS * BH;
                out[tail + (size_t)b * HD + j]      = h_out;
                out[tail + BH + (size_t)b * HD + j] = c_out;
            }

            // prefetch next step's gate inputs + mask
            int tn = (t + 1 < T_STEPS) ? t + 1 : t;
            #pragma unroll
            for (int g = 0; g < 4; g++)
                xg[g] = (float)x4[((size_t)tn * BATCH + b) * 4096 + g * HD + j];
            mv = mask[tn * BATCH + b];
        }
        bi = wi;
    }
}

// ---------------- tier A/B persistent kernel (proven) ----------------
template<bool XF16>
__global__ __launch_bounds__(1024, 4) void lstm_persist(
    const float* __restrict__ X, const _Float16* __restrict__ xh,
    const float* __restrict__ h0, const float* __restrict__ c0,
    const float* __restrict__ bias, const int* __restrict__ mask,
    const _Float16* __restrict__ wx16, const _Float16* __restrict__ whh,
    const _Float16* __restrict__ whl,
    _Float16* __restrict__ chg, _Float16* __restrict__ clg,
    int* __restrict__ barg, int* __restrict__ barr,
    float* __restrict__ out)
{
    __shared__ _Float16 s_wh[16 * 1032];
    __shared__ float    s_pre[16][16][17];
    __shared__ float    s_h[256], s_c[256];

    const int tid  = threadIdx.x;
    const int wave = tid >> 6;
    const int lane = tid & 63;
    const int j0   = blockIdx.x * 4;

    for (int idx = tid; idx < 2048; idx += 1024) {
        int n  = idx >> 7;
        int kk = (idx & 127) << 3;
        int r  = (n >> 2) * HD + j0 + (n & 3);
        *(half8*)&s_wh[n * 1032 + kk] = *(const half8*)(whh + (size_t)r * HD + kk);
    }

    float biasr[4] = {0.f, 0.f, 0.f, 0.f};
    if (tid < 256) {
        int b = tid >> 2, jj = tid & 3, j = j0 + jj;
        float cv = c0[b * HD + j];
        s_c[tid] = cv;
        s_h[tid] = h0[b * HD + j];
        _Float16 hi = (_Float16)cv;
        chg[b * HD + j] = hi;
        clg[b * HD + j] = (_Float16)(cv - (float)hi);
        #pragma unroll
        for (int g = 0; g < 4; g++) biasr[g] = bias[g * HD + j];
    }
    grid_bar(barg, barr, 0);

    const int mt    = wave & 3;
    const int kh    = wave >> 2;
    const int arow  = mt * 16 + (lane & 15);
    const int nn    = lane & 15;
    const int q     = lane >> 4;
    const int kbase = kh * 256 + q * 8;
    const int wrow  = (nn >> 2) * HD + j0 + (nn & 3);

    const _Float16* wxp = wx16 + (size_t)wrow * HD + kbase;
    const _Float16* wlp = whl  + (size_t)wrow * HD + kbase;
    const _Float16* whp = (const _Float16*)&s_wh[nn * 1032 + kbase];

    for (int t = 0; t < T_STEPS; t++) {
        const int cur = t & 1;
        const _Float16* chp = chg + (size_t)cur * BH + (size_t)arow * HD + kbase;
        const _Float16* clp = clg + (size_t)cur * BH + (size_t)arow * HD + kbase;

        floatx4 acc = {0.f, 0.f, 0.f, 0.f};

        if (XF16) {
            const _Float16* xp = xh + (size_t)t * BH + (size_t)arow * HD + kbase;
            #pragma unroll 4
            for (int k = 0; k < 256; k += 32) {
                half8 av = *(const half8*)(xp + k);
                half8 bv = *(const half8*)(wxp + k);
                acc = __builtin_amdgcn_mfma_f32_16x16x32_f16(av, bv, acc, 0, 0, 0);
            }
        } else {
            const float* xp = X + (size_t)t * BH + (size_t)arow * HD + kbase;
            #pragma unroll 4
            for (int k = 0; k < 256; k += 32) {
                float4v x0 = *(const float4v*)(xp + k);
                float4v x1 = *(const float4v*)(xp + k + 4);
                half8 av = cvt_h8(x0, x1);
                half8 bv = *(const half8*)(wxp + k);
                acc = __builtin_amdgcn_mfma_f32_16x16x32_f16(av, bv, acc, 0, 0, 0);
            }
        }

        #pragma unroll 4
        for (int k = 0; k < 256; k += 32) {
            half8 ah = *(const half8*)(chp + k);
            half8 al = *(const half8*)(clp + k);
            half8 bh = *(const half8*)(whp + k);
            half8 bl = *(const half8*)(wlp + k);
            acc = __builtin_amdgcn_mfma_f32_16x16x32_f16(ah, bh, acc, 0, 0, 0);
            acc = __builtin_amdgcn_mfma_f32_16x16x32_f16(al, bh, acc, 0, 0, 0);
            acc = __builtin_amdgcn_mfma_f32_16x16x32_f16(ah, bl, acc, 0, 0, 0);
        }

        s_pre[wave][q * 4 + 0][nn] = acc[0];
        s_pre[wave][q * 4 + 1][nn] = acc[1];
        s_pre[wave][q * 4 + 2][nn] = acc[2];
        s_pre[wave][q * 4 + 3][nn] = acc[3];
        __syncthreads();

        if (tid < 256) {
            int b = tid >> 2, jj = tid & 3, j = j0 + jj;
            int m = b & 15, mtt = b >> 4;

            float pg[4];
            #pragma unroll
            for (int g = 0; g < 4; g++) {
                float s = 0.f;
                #pragma unroll
                for (int kk = 0; kk < 4; kk++)
                    s += s_pre[kk * 4 + mtt][m][g * 4 + jj];
                pg[g] = s + biasr[g];
            }

            float c_old = s_c[tid];
            float i_g = sigmoidf_(pg[0]);
            float f_g = sigmoidf_(pg[1]);
            float o_g = sigmoidf_(pg[2]);
            float g_g = tanhf(pg[3]);
            float c_new = f_g * c_old + i_g * g_g;
            float h_new = o_g * tanhf(c_new);

            int mv = mask[t * BATCH + b];
            float h_out = mv ? h_new : s_h[tid];
            float c_out = mv ? c_new : c_old;
            s_h[tid] = h_out;
            s_c[tid] = c_out;

            int nxt = cur ^ 1;
            _Float16 hi = (_Float16)c_out;
            chg[(size_t)nxt * BH + b * HD + j] = hi;
            clg[(size_t)nxt * BH + b * HD + j] = (_Float16)(c_out - (float)hi);
            out[(size_t)t * BH + b * HD + j] = h_out;

            if (t == T_STEPS - 1) {
                size_t tail = (size_t)T_STEPS * BH;
                out[tail + b * HD + j]      = h_out;
                out[tail + BH + b * HD + j] = c_out;
            }
        }
        grid_bar(barg, barr, t + 1);
    }
}

// ---------------- tiny-ws fallback: per-step kernel ----------------
__global__ void init_c_fb(const float* __restrict__ c0, float* __restrict__ cf,
                          _Float16* __restrict__ ch, _Float16* __restrict__ cl) {
    int i = blockIdx.x * 256 + threadIdx.x;
    if (i < BH) {
        float v = c0[i];
        cf[i] = v;
        _Float16 h = (_Float16)v;
        ch[i] = h;
        cl[i] = (_Float16)(v - (float)h);
    }
}

__global__ __launch_bounds__(1024) void lstm_step_fb(
    const float* __restrict__ X, const float* __restrict__ h0,
    const float* __restrict__ Wx, const float* __restrict__ Wh,
    const float* __restrict__ bias, const int* __restrict__ mask,
    float* __restrict__ cf, _Float16* __restrict__ chbuf, _Float16* __restrict__ clbuf,
    float* __restrict__ out, int t)
{
    __shared__ float lds_pre[4][64][16];
    const int tid = threadIdx.x, wave = tid >> 6, lane = tid & 63;
    const int g = wave & 3, mt = wave >> 2, j0 = blockIdx.x * 16;
    const int cur = t & 1;
    const float* cf_prev = cf + (size_t)cur * BH;
    const _Float16* ch_prev = chbuf + (size_t)cur * BH;
    const _Float16* cl_prev = clbuf + (size_t)cur * BH;
    float* cf_next = cf + (size_t)(cur ^ 1) * BH;
    _Float16* ch_next = chbuf + (size_t)(cur ^ 1) * BH;
    _Float16* cl_next = clbuf + (size_t)(cur ^ 1) * BH;
    const int arow = mt * 16 + (lane & 15);
    const int brow = g * HD + j0 + (lane & 15);
    const int koff = (lane >> 4) * 8;
    floatx4 acc = {0.f, 0.f, 0.f, 0.f};
    {
        const float* xp = X + (size_t)t * BH + (size_t)arow * HD + koff;
        const float* wp = Wx + (size_t)brow * HD + koff;
        #pragma unroll 4
        for (int k = 0; k < HD; k += 32) {
            float4v x0 = *(const float4v*)(xp + k);
            float4v x1 = *(const float4v*)(xp + k + 4);
            float4v w0 = *(const float4v*)(wp + k);
            float4v w1 = *(const float4v*)(wp + k + 4);
            acc = __builtin_amdgcn_mfma_f32_16x16x32_f16(cvt_h8(x0, x1), cvt_h8(w0, w1), acc, 0, 0, 0);
        }
    }
    {
        const _Float16* chp = ch_prev + (size_t)arow * HD + koff;
        const _Float16* clp = cl_prev + (size_t)arow * HD + koff;
        const float* whp = Wh + (size_t)brow * HD + koff;
        #pragma unroll 4
        for (int k = 0; k < HD; k += 32) {
            half8 ah = *(const half8*)(chp + k);
            half8 al = *(const half8*)(clp + k);
            float4v w0 = *(const float4v*)(whp + k);
            float4v w1 = *(const float4v*)(whp + k + 4);
            half8 bh = cvt_h8(w0, w1);
            float4v r0, r1;
            r0[0] = w0[0] - (float)bh[0]; r0[1] = w0[1] - (float)bh[1];
            r0[2] = w0[2] - (float)bh[2]; r0[3] = w0[3] - (float)bh[3];
            r1[0] = w1[0] - (float)bh[4]; r1[1] = w1[1] - (float)bh[5];
            r1[2] = w1[2] - (float)bh[6]; r1[3] = w1[7 - 7] - (float)bh[7];
            r1[3] = w1[3] - (float)bh[7];
            half8 bl = cvt_h8(r0, r1);
            acc = __builtin_amdgcn_mfma_f32_16x16x32_f16(ah, bh, acc, 0, 0, 0);
            acc = __builtin_amdgcn_mfma_f32_16x16x32_f16(al, bh, acc, 0, 0, 0);
            acc = __builtin_amdgcn_mfma_f32_16x16x32_f16(ah, bl, acc, 0, 0, 0);
        }
    }
    {
        const int qq = lane >> 4, col = lane & 15;
        lds_pre[g][mt * 16 + qq * 4 + 0][col] = acc[0];
        lds_pre[g][mt * 16 + qq * 4 + 1][col] = acc[1];
        lds_pre[g][mt * 16 + qq * 4 + 2][col] = acc[2];
        lds_pre[g][mt * 16 + qq * 4 + 3][col] = acc[3];
    }
    __syncthreads();
    {
        const int bl2 = tid >> 4, n = tid & 15, j = j0 + n;
        float pg[4];
        #pragma unroll
        for (int gg = 0; gg < 4; gg++) pg[gg] = lds_pre[gg][bl2][n] + bias[gg * HD + j];
        float c_old = cf_prev[bl2 * HD + j];
        float i_g = sigmoidf_(pg[0]), f_g = sigmoidf_(pg[1]);
        float o_g = sigmoidf_(pg[2]), g_g = tanhf(pg[3]);
        float c_new = f_g * c_old + i_g * g_g;
        float h_new = o_g * tanhf(c_new);
        int mv = mask[t * BATCH + bl2];
        float h_prev = (t == 0) ? h0[bl2 * HD + j] : out[(size_t)(t - 1) * BH + bl2 * HD + j];
        float h_out = mv ? h_new : h_prev;
        float c_out = mv ? c_new : c_old;
        cf_next[bl2 * HD + j] = c_out;
        _Float16 hh = (_Float16)c_out;
        ch_next[bl2 * HD + j] = hh;
        cl_next[bl2 * HD + j] = (_Float16)(c_out - (float)hh);
        out[(size_t)t * BH + bl2 * HD + j] = h_out;
        if (t == T_STEPS - 1) {
            size_t tail = (size_t)T_STEPS * BH;
            out[tail + bl2 * HD + j] = h_out;
            out[tail + BH + bl2 * HD + j] = c_out;
        }
    }
}

// ---------------- launch ----------------
extern "C" void kernel_launch(void* const* d_in, const int* in_sizes, int n_in,
                              void* d_out, int out_size, void* d_ws, size_t ws_size,
                              hipStream_t stream) {
    const float* X    = (const float*)d_in[0];
    const float* h0   = (const float*)d_in[1];
    const float* c0   = (const float*)d_in[2];
    const int*   mask = (const int*)  d_in[3];
    const float* Wx   = (const float*)d_in[4];
    const float* Wh   = (const float*)d_in[5];
    const float* bias = (const float*)d_in[6];
    float* out = (float*)d_out;
    char* ws = (char*)d_ws;

    if (ws_size >= TIER_B_WS) {
        int*      barg = (int*)(ws + BAR_GRP_OFF);
        int*      barr = (int*)(ws + BAR_ROOT_OFF);
        _Float16* chg  = (_Float16*)(ws + CH_OFF);
        _Float16* clg  = (_Float16*)(ws + CL_OFF);
        _Float16* wx16 = (_Float16*)(ws + WX_OFF);
        _Float16* whh  = (_Float16*)(ws + WHH_OFF);
        _Float16* whl  = (_Float16*)(ws + WHL_OFF);

        prep_w<<<dim3(16384), dim3(256), 0, stream>>>(Wx, Wh, wx16, whh, whl);

        if (ws_size >= TIER_A2_WS) {
            char* c3 = ws + CH_OFF;   // 3 x 256KB tagged c buffers
            _Float16* x4 = (_Float16*)(ws + X4_OFF);
            prep_poison<<<dim3(768), dim3(256), 0, stream>>>((unsigned*)c3);
            x4_gemm<<<dim3(256, 32), dim3(256), 0, stream>>>(X, wx16, x4);
            void* args[] = {
                (void*)&x4, (void*)&h0, (void*)&c0, (void*)&bias, (void*)&mask,
                (void*)&whh, (void*)&whl, (void*)&c3, (void*)&out
            };
            hipLaunchCooperativeKernel((const void*)&lstm_persist5,
                                       dim3(NBLK), dim3(512), args, 0, stream);
        } else {
            prep_zero<<<dim3(24), dim3(256), 0, stream>>>(barg);
            _Float16* xh = (_Float16*)(ws + XH_OFF);
            const bool tierA = ws_size >= TIER_A_WS;
            if (tierA)
                prep_x<<<dim3(131072), dim3(256), 0, stream>>>(X, xh);
            void* args[] = {
                (void*)&X, (void*)&xh, (void*)&h0, (void*)&c0, (void*)&bias,
                (void*)&mask, (void*)&wx16, (void*)&whh, (void*)&whl,
                (void*)&chg, (void*)&clg, (void*)&barg, (void*)&barr, (void*)&out
            };
            if (tierA)
                hipLaunchCooperativeKernel((const void*)&lstm_persist<true>,
                                           dim3(NBLK), dim3(1024), args, 0, stream);
            else
                hipLaunchCooperativeKernel((const void*)&lstm_persist<false>,
                                           dim3(NBLK), dim3(1024), args, 0, stream);
        }
    } else {
        float*    cf = (float*)ws;
        _Float16* ch = (_Float16*)(ws + 524288);
        _Float16* cl = (_Float16*)(ws + 786432);
        init_c_fb<<<dim3((BH + 255) / 256), dim3(256), 0, stream>>>(c0, cf, ch, cl);
        for (int t = 0; t < T_STEPS; t++)
            lstm_step_fb<<<dim3(64), dim3(1024), 0, stream>>>(
                X, h0, Wx, Wh, bias, mask, cf, ch, cl, out, t);
    }
}